// Round 8
// baseline (102.710 us; speedup 1.0000x reference)
//
#include <hip/hip_runtime.h>

#define B_ 4
#define S_ 1024
#define D_ 1024
#define H_ 16
#define BSD (B_*S_*D_)

typedef unsigned short ushort_t;
typedef __attribute__((ext_vector_type(8))) __bf16 bf16x8;
typedef __attribute__((ext_vector_type(8))) ushort_t ushortx8;
typedef __attribute__((ext_vector_type(4))) float f32x4;

__device__ __forceinline__ ushort_t f2bf(float f) {
  union { float f; unsigned int u; } x; x.f = f;
  unsigned int r = x.u + 0x7fffu + ((x.u >> 16) & 1u);
  return (ushort_t)(r >> 16);
}

__device__ __forceinline__ void gll16(const void* g, void* l) {
  __builtin_amdgcn_global_load_lds(
      (const __attribute__((address_space(1))) unsigned int*)g,
      (__attribute__((address_space(3))) unsigned int*)l, 16, 0, 0);
}

// Phase barrier with NO vmcnt: publish ds_writes, sync, fence reads after.
#define PBAR() do { asm volatile("s_waitcnt lgkmcnt(0)" ::: "memory"); \
                    __builtin_amdgcn_s_barrier(); \
                    asm volatile("" ::: "memory"); } while (0)

// ---------------- transpose weights -> bf16 [N][K] ----------------
__global__ __launch_bounds__(256) void transpose_w(
    const float* __restrict__ Wq, const float* __restrict__ Wk,
    const float* __restrict__ Wv, const float* __restrict__ Wo,
    ushort_t* __restrict__ WqT, ushort_t* __restrict__ WkT,
    ushort_t* __restrict__ WvT, ushort_t* __restrict__ WoT)
{
  __shared__ float tile[64][65];
  int blk = blockIdx.x;
  const float* src; ushort_t* dst;
  size_t sbase, dbase; int ld_src, ld_dst, r0, c0;
  if (blk < 768) {
    int tz = blk / 256;
    int rem = blk % 256; int head = rem >> 4; int kt = rem & 15;
    src = (tz == 0) ? Wq : (tz == 1) ? Wk : Wv;
    dst = (tz == 0) ? WqT : (tz == 1) ? WkT : WvT;
    sbase = (size_t)head * 1024 * 64; dbase = (size_t)head * 64 * 1024;
    ld_src = 64; ld_dst = 1024; r0 = kt * 64; c0 = 0;
  } else {
    int idx = blk - 768; src = Wo; dst = WoT;
    sbase = 0; dbase = 0; ld_src = 1024; ld_dst = 1024;
    r0 = (idx >> 4) * 64; c0 = (idx & 15) * 64;
  }
  int tid = threadIdx.x; int col = tid & 63; int rbase = tid >> 6;
  #pragma unroll
  for (int j = 0; j < 16; ++j) {
    int row = j * 4 + rbase;
    tile[row][col] = src[sbase + (size_t)(r0 + row) * ld_src + c0 + col];
  }
  __syncthreads();
  #pragma unroll
  for (int j = 0; j < 16; ++j) {
    int orow = j * 4 + rbase;   // source col
    dst[dbase + (size_t)(c0 + orow) * ld_dst + r0 + col] = f2bf(tile[col][orow]);
  }
}

// ---------------- 128x128 reg-pipelined GEMM, f32 A (proj) ----------------
// Round-5 structure (best measured). Both operands global->reg (iter t) -> LDS
// (iter t+1); PBAR has no vmcnt, loads age a full iteration before consume.
__device__ __forceinline__ void gemm_pipe_f32A(
    const float* __restrict__ Af, const ushort_t* __restrict__ BT,
    ushort_t* __restrict__ Cb, int epi, int m0, int n0, int K)
{
  __shared__ __align__(16) ushort_t As[2][128 * 64];
  __shared__ __align__(16) ushort_t Bs[2][128 * 64];
  const int tid = threadIdx.x;
  const int wave = tid >> 6, lane = tid & 63;
  const int wm = wave >> 2, wn = wave & 3;   // wave tile: 64 (m) x 32 (n)

  f32x4 acc[4][2] = {};
  float4   ra0[2][2], ra1[2][2];   // ping-pong A f32  [segment][half]
  ushortx8 rb0[2],    rb1[2];      // ping-pong B bf16 [segment]

  int offs[2], gofs[2];
  #pragma unroll
  for (int i = 0; i < 2; ++i) {
    int off = ((i * 8 + wave) << 10) + lane * 16;
    int row = off >> 7, cb = off & 127;
    int lcb = cb ^ ((row & 7) << 4);
    offs[i] = off;
    gofs[i] = row * K + (lcb >> 1);
  }

  auto loadAB = [&](float4 (&ar)[2][2], ushortx8 (&br)[2], int k0) {
    #pragma unroll
    for (int i = 0; i < 2; ++i) {
      const float* asrc = Af + (size_t)m0 * K + gofs[i] + k0;
      ar[i][0] = *(const float4*)(asrc);
      ar[i][1] = *(const float4*)(asrc + 4);
      br[i] = *(const ushortx8*)(BT + (size_t)n0 * K + gofs[i] + k0);
    }
  };
  auto writeAB = [&](int buf, const float4 (&ar)[2][2], const ushortx8 (&br)[2]) {
    #pragma unroll
    for (int i = 0; i < 2; ++i) {
      ushortx8 tv;
      #pragma unroll
      for (int j = 0; j < 4; ++j) {
        tv[j]     = f2bf(((const float*)&ar[i][0])[j]);
        tv[4 + j] = f2bf(((const float*)&ar[i][1])[j]);
      }
      *(ushortx8*)((char*)As[buf] + offs[i]) = tv;
      *(ushortx8*)((char*)Bs[buf] + offs[i]) = br[i];
    }
  };
  auto compute = [&](int buf) {
    #pragma unroll
    for (int kk = 0; kk < 2; ++kk) {
      bf16x8 af[4], bfr[2];
      #pragma unroll
      for (int mf = 0; mf < 4; ++mf) {
        int row = wm * 64 + mf * 16 + (lane & 15);
        int cb = kk * 64 + ((lane >> 4) << 4);
        af[mf] = *(const bf16x8*)((const char*)As[buf] + (row << 7) + (cb ^ ((row & 7) << 4)));
      }
      #pragma unroll
      for (int nf = 0; nf < 2; ++nf) {
        int row = wn * 32 + nf * 16 + (lane & 15);
        int cb = kk * 64 + ((lane >> 4) << 4);
        bfr[nf] = *(const bf16x8*)((const char*)Bs[buf] + (row << 7) + (cb ^ ((row & 7) << 4)));
      }
      #pragma unroll
      for (int mf = 0; mf < 4; ++mf)
        #pragma unroll
        for (int nf = 0; nf < 2; ++nf)
          acc[mf][nf] = __builtin_amdgcn_mfma_f32_16x16x32_bf16(af[mf], bfr[nf], acc[mf][nf], 0, 0, 0);
    }
  };

  const int nt = K >> 6;   // 16; even
  loadAB(ra0, rb0, 0);
  writeAB(0, ra0, rb0);          // prologue: one exposed wait for tile0
  loadAB(ra1, rb1, 64);
  PBAR();

  for (int t = 0; t < nt - 3; t += 2) {
    loadAB(ra0, rb0, (t + 2) << 6);
    __builtin_amdgcn_sched_barrier(0);
    compute(0);                  // tile t
    writeAB(1, ra1, rb1);        // tile t+1 (regs aged ~1 iteration)
    PBAR();
    loadAB(ra1, rb1, (t + 3) << 6);
    __builtin_amdgcn_sched_barrier(0);
    compute(1);                  // tile t+1
    writeAB(0, ra0, rb0);        // tile t+2
    PBAR();
  }
  // buf0 = tile nt-2; regs ra1/rb1 = tile nt-1
  compute(0);
  writeAB(1, ra1, rb1);
  PBAR();
  compute(1);

  #pragma unroll
  for (int mf = 0; mf < 4; ++mf) {
    #pragma unroll
    for (int nf = 0; nf < 2; ++nf) {
      #pragma unroll
      for (int r = 0; r < 4; ++r) {
        int m = m0 + wm * 64 + mf * 16 + ((lane >> 4) << 2) + r;
        int n = n0 + wn * 32 + nf * 16 + (lane & 15);
        float val = acc[mf][nf][r];
        if (epi == 0) {           // qh/kh: [B,H,S,64]
          int b = m >> 10, s = m & 1023, h = n >> 6, dk = n & 63;
          Cb[((((size_t)(b * H_ + h)) << 10) + s) * 64 + dk] = f2bf(val);
        } else {                  // vhT: [B,H,64,S]
          int b = m >> 10, s = m & 1023, h = n >> 6, dv = n & 63;
          Cb[((((size_t)(b * H_ + h)) * 64 + dv) << 10) + s] = f2bf(val);
        }
      }
    }
  }
}

// ---------------- 128x128 reg-pipelined GEMM, bf16 A (out_gemm) ----------------
__device__ __forceinline__ void gemm_pipe_bf16(
    const ushort_t* __restrict__ A, const ushort_t* __restrict__ BT,
    float* __restrict__ Cf, int m0, int n0, int K)
{
  __shared__ __align__(16) ushort_t As[2][128 * 64];
  __shared__ __align__(16) ushort_t Bs[2][128 * 64];
  const int tid = threadIdx.x;
  const int wave = tid >> 6, lane = tid & 63;
  const int wm = wave >> 2, wn = wave & 3;

  f32x4 acc[4][2] = {};
  ushortx8 ra0[2], ra1[2], rb0[2], rb1[2];

  int offs[2], gofs[2];
  #pragma unroll
  for (int i = 0; i < 2; ++i) {
    int off = ((i * 8 + wave) << 10) + lane * 16;
    int row = off >> 7, cb = off & 127;
    int lcb = cb ^ ((row & 7) << 4);
    offs[i] = off;
    gofs[i] = row * K + (lcb >> 1);
  }

  auto loadAB = [&](ushortx8 (&ar)[2], ushortx8 (&br)[2], int k0) {
    #pragma unroll
    for (int i = 0; i < 2; ++i) {
      ar[i] = *(const ushortx8*)(A  + (size_t)m0 * K + gofs[i] + k0);
      br[i] = *(const ushortx8*)(BT + (size_t)n0 * K + gofs[i] + k0);
    }
  };
  auto writeAB = [&](int buf, const ushortx8 (&ar)[2], const ushortx8 (&br)[2]) {
    #pragma unroll
    for (int i = 0; i < 2; ++i) {
      *(ushortx8*)((char*)As[buf] + offs[i]) = ar[i];
      *(ushortx8*)((char*)Bs[buf] + offs[i]) = br[i];
    }
  };
  auto compute = [&](int buf) {
    #pragma unroll
    for (int kk = 0; kk < 2; ++kk) {
      bf16x8 af[4], bfr[2];
      #pragma unroll
      for (int mf = 0; mf < 4; ++mf) {
        int row = wm * 64 + mf * 16 + (lane & 15);
        int cb = kk * 64 + ((lane >> 4) << 4);
        af[mf] = *(const bf16x8*)((const char*)As[buf] + (row << 7) + (cb ^ ((row & 7) << 4)));
      }
      #pragma unroll
      for (int nf = 0; nf < 2; ++nf) {
        int row = wn * 32 + nf * 16 + (lane & 15);
        int cb = kk * 64 + ((lane >> 4) << 4);
        bfr[nf] = *(const bf16x8*)((const char*)Bs[buf] + (row << 7) + (cb ^ ((row & 7) << 4)));
      }
      #pragma unroll
      for (int mf = 0; mf < 4; ++mf)
        #pragma unroll
        for (int nf = 0; nf < 2; ++nf)
          acc[mf][nf] = __builtin_amdgcn_mfma_f32_16x16x32_bf16(af[mf], bfr[nf], acc[mf][nf], 0, 0, 0);
    }
  };

  const int nt = K >> 6;
  loadAB(ra0, rb0, 0);
  writeAB(0, ra0, rb0);
  loadAB(ra1, rb1, 64);
  PBAR();

  for (int t = 0; t < nt - 3; t += 2) {
    loadAB(ra0, rb0, (t + 2) << 6);
    __builtin_amdgcn_sched_barrier(0);
    compute(0);
    writeAB(1, ra1, rb1);
    PBAR();
    loadAB(ra1, rb1, (t + 3) << 6);
    __builtin_amdgcn_sched_barrier(0);
    compute(1);
    writeAB(0, ra0, rb0);
    PBAR();
  }
  compute(0);
  writeAB(1, ra1, rb1);
  PBAR();
  compute(1);

  #pragma unroll
  for (int mf = 0; mf < 4; ++mf) {
    #pragma unroll
    for (int nf = 0; nf < 2; ++nf) {
      #pragma unroll
      for (int r = 0; r < 4; ++r) {
        int m = m0 + wm * 64 + mf * 16 + ((lane >> 4) << 2) + r;
        int n = n0 + wn * 32 + nf * 16 + (lane & 15);
        Cf[(size_t)m * 1024 + n] = acc[mf][nf][r];
      }
    }
  }
}

// proj: 1-D grid 768, NATURAL interleave (no XCD chunking): each (z,x) group is
// 8 consecutive block IDs -> its y-blocks (and any DEAD group) span all 8 XCDs
// under round-robin dispatch. With ~57% live blocks (< 512 co-resident slots),
// balanced spread collapses proj to ~one round of T_block.
__global__ __launch_bounds__(512, 4) void proj_gemm(
    const float* q, const float* k, const float* v,
    const ushort_t* WqT, const ushort_t* WkT, const ushort_t* WvT,
    const int* __restrict__ pad1p, const int* __restrict__ pad2p,
    ushort_t* qh, ushort_t* kh, ushort_t* vhT)
{
  int f = blockIdx.x;
  int combo = f >> 3;             // 0..95 : (z,x)
  int y = f & 7;
  int z = combo >> 5, x = combo & 31;
  if (z < 2) {                    // q (z=0) gated by pad2, k (z=1) by pad1
    int b = x >> 3;
    int s0 = (x & 7) << 7;
    int lim = (z == 0) ? pad2p[b] : pad1p[b];
    if (s0 >= lim) return;        // wave-uniform early exit
  }
  const float* A = (z == 0) ? q : (z == 1) ? k : v;
  const ushort_t* BT = (z == 0) ? WqT : (z == 1) ? WkT : WvT;
  ushort_t* C = (z == 0) ? qh : (z == 1) ? kh : vhT;
  gemm_pipe_f32A(A, BT, C, (z == 2) ? 1 : 0, x * 128, y * 128, 1024);
}

__global__ __launch_bounds__(512, 4) void out_gemm(
    const ushort_t* o, const ushort_t* WoT, float* out)
{
  int f = blockIdx.x;
  int xcd = f & 7;
  int slot = f >> 3;              // 0..31
  int x = xcd * 4 + (slot >> 3);  // 0..31
  int y = slot & 7;
  gemm_pipe_bf16(o, WoT, out, x * 128, y * 128, 1024);
}

// ---------------- V-mean per (b,h,dv) for fully-masked rows ----------------
__global__ __launch_bounds__(256) void meanv_kernel(
    const ushort_t* __restrict__ vhT, float* __restrict__ meanV)
{
  int row = blockIdx.x * 4 + (threadIdx.x >> 6);   // bh*64 + dv
  int lane = threadIdx.x & 63;
  const ushort_t* src = vhT + ((size_t)row << 10) + lane * 16;
  float s = 0.f;
  #pragma unroll
  for (int i = 0; i < 2; ++i) {
    bf16x8 v = *(const bf16x8*)(src + i * 8);
    #pragma unroll
    for (int j = 0; j < 8; ++j) s += (float)v[j];
  }
  #pragma unroll
  for (int mm = 1; mm < 64; mm <<= 1) s += __shfl_xor(s, mm);
  if (lane == 0) meanV[row] = s * (1.0f / 1024.0f);
}

// ---------------- flash attention ----------------
__global__ __launch_bounds__(256) void attn_kernel(
    const ushort_t* __restrict__ qh, const ushort_t* __restrict__ kh,
    const ushort_t* __restrict__ vhT, const float* __restrict__ meanV,
    const int* __restrict__ pad1p, const int* __restrict__ pad2p,
    ushort_t* __restrict__ o)
{
  const int bh = blockIdx.x;
  const int b = bh >> 4, h = bh & 15;
  const int q0 = blockIdx.y << 6;
  const int pad1 = pad1p[b], pad2 = pad2p[b];
  const int tid = threadIdx.x, wave = tid >> 6, lane = tid & 63;

  if (q0 >= pad2) {   // whole tile dead: softmax of all -1e10 -> uniform -> meanV
    int dv = tid & 63;
    int rw = tid >> 6;
    ushort_t mb = f2bf(meanV[(bh << 6) + dv]);
    for (int r = rw; r < 64; r += 4)
      o[(((size_t)((b << 10) + q0 + r)) << 10) + (h << 6) + dv] = mb;
    return;
  }

  __shared__ __align__(16) ushort_t Ks[64 * 64];
  __shared__ __align__(16) ushort_t Vs[64 * 64];
  __shared__ __align__(16) ushort_t Ps[4][16 * 64];

  const ushort_t* qbase = qh + ((size_t)bh << 16);
  const ushort_t* kbase = kh + ((size_t)bh << 16);
  const ushort_t* vbase = vhT + ((size_t)bh << 16);

  const int qrow = q0 + wave * 16 + (lane & 15);
  bf16x8 qf[2];
  qf[0] = *(const bf16x8*)(qbase + (size_t)qrow * 64 + ((lane >> 4) << 3));
  qf[1] = *(const bf16x8*)(qbase + (size_t)qrow * 64 + 32 + ((lane >> 4) << 3));

  f32x4 acc[4] = {};
  float mrow[4] = { -1e30f, -1e30f, -1e30f, -1e30f };
  float lrow[4] = { 0.f, 0.f, 0.f, 0.f };
  const int ribase = q0 + wave * 16 + ((lane >> 4) << 2);

  int t_hi = min(q0 + 63, min(pad2 - 1, pad1 - 1));
  int nb = (t_hi >> 6) + 1;

  for (int kb = 0; kb < nb; ++kb) {
    const int t0 = kb << 6;
    #pragma unroll
    for (int i = 0; i < 2; ++i) {
      int off = ((i * 4 + wave) << 10) + lane * 16;
      int row = off >> 7;
      int cb = off & 127;
      int lcb = cb ^ ((row & 7) << 4);
      gll16(kbase + (size_t)(t0 + row) * 64 + (lcb >> 1), (char*)Ks + off);
      gll16(vbase + ((size_t)row << 10) + t0 + (lcb >> 1), (char*)Vs + off);
    }
    __syncthreads();

    f32x4 sc[4];
    #pragma unroll
    for (int nf = 0; nf < 4; ++nf) {
      sc[nf] = (f32x4){0.f, 0.f, 0.f, 0.f};
      #pragma unroll
      for (int kk = 0; kk < 2; ++kk) {
        int trow = nf * 16 + (lane & 15);
        int cb = kk * 64 + ((lane >> 4) << 4);
        bf16x8 kf = *(const bf16x8*)((const char*)Ks + (trow << 7) + (cb ^ ((trow & 7) << 4)));
        sc[nf] = __builtin_amdgcn_mfma_f32_16x16x32_bf16(qf[kk], kf, sc[nf], 0, 0, 0);
      }
    }

    float pv[4][4];
    #pragma unroll
    for (int r = 0; r < 4; ++r) {
      const int irow = ribase + r;
      float sval[4];
      float rmax = -1e30f;
      #pragma unroll
      for (int nf = 0; nf < 4; ++nf) {
        int t = t0 + nf * 16 + (lane & 15);
        float vv = sc[nf][r] * 0.125f;
        if (t > irow || t >= pad1) vv = -1e10f;
        sval[nf] = vv;
        rmax = fmaxf(rmax, vv);
      }
      #pragma unroll
      for (int mm = 1; mm < 16; mm <<= 1) rmax = fmaxf(rmax, __shfl_xor(rmax, mm));
      float nm = fmaxf(mrow[r], rmax);
      float fscale = __expf(mrow[r] - nm);
      float rsum = 0.f;
      #pragma unroll
      for (int nf = 0; nf < 4; ++nf) {
        float p = __expf(sval[nf] - nm);
        pv[nf][r] = p;
        rsum += p;
      }
      #pragma unroll
      for (int mm = 1; mm < 16; mm <<= 1) rsum += __shfl_xor(rsum, mm);
      mrow[r] = nm;
      lrow[r] = lrow[r] * fscale + rsum;
      #pragma unroll
      for (int dvf = 0; dvf < 4; ++dvf) acc[dvf][r] *= fscale;
    }

    #pragma unroll
    for (int nf = 0; nf < 4; ++nf) {
      #pragma unroll
      for (int r = 0; r < 4; ++r) {
        int prow = ((lane >> 4) << 2) + r;
        int cbw = (nf * 16 + (lane & 15)) * 2;
        *(ushort_t*)((char*)Ps[wave] + (prow << 7) + (cbw ^ ((prow & 7) << 4))) = f2bf(pv[nf][r]);
      }
    }

    #pragma unroll
    for (int kk = 0; kk < 2; ++kk) {
      int prow = lane & 15;
      int cb = kk * 64 + ((lane >> 4) << 4);
      bf16x8 pf = *(const bf16x8*)((const char*)Ps[wave] + (prow << 7) + (cb ^ ((prow & 7) << 4)));
      #pragma unroll
      for (int dvf = 0; dvf < 4; ++dvf) {
        int vrow = dvf * 16 + (lane & 15);
        bf16x8 vfr = *(const bf16x8*)((const char*)Vs + (vrow << 7) + (cb ^ ((vrow & 7) << 4)));
        acc[dvf] = __builtin_amdgcn_mfma_f32_16x16x32_bf16(pf, vfr, acc[dvf], 0, 0, 0);
      }
    }
    __syncthreads();
  }

  #pragma unroll
  for (int dvf = 0; dvf < 4; ++dvf) {
    #pragma unroll
    for (int r = 0; r < 4; ++r) {
      int irow = ribase + r;
      int dv = dvf * 16 + (lane & 15);
      float val;
      if (irow < pad2) val = acc[dvf][r] * (1.0f / lrow[r]);
      else val = meanV[(bh << 6) + dv];
      o[(((size_t)((b << 10) + irow)) << 10) + (h << 6) + dv] = f2bf(val);
    }
  }
}

extern "C" void kernel_launch(void* const* d_in, const int* in_sizes, int n_in,
                              void* d_out, int out_size, void* d_ws, size_t ws_size,
                              hipStream_t stream) {
  (void)in_sizes; (void)n_in; (void)out_size; (void)ws_size;
  const float* q = (const float*)d_in[0];
  const float* k = (const float*)d_in[1];
  const float* v = (const float*)d_in[2];
  const int* pad1 = (const int*)d_in[3];
  const int* pad2 = (const int*)d_in[4];
  const float* Wq = (const float*)d_in[5];
  const float* Wk = (const float*)d_in[6];
  const float* Wv = (const float*)d_in[7];
  const float* Wo = (const float*)d_in[8];
  float* out = (float*)d_out;

  char* ws = (char*)d_ws;
  const size_t MB = 1u << 20;
  ushort_t* WqT = (ushort_t*)(ws + 24 * MB);
  ushort_t* WkT = (ushort_t*)(ws + 26 * MB);
  ushort_t* WvT = (ushort_t*)(ws + 28 * MB);
  ushort_t* WoT = (ushort_t*)(ws + 30 * MB);
  ushort_t* qh  = (ushort_t*)(ws + 32 * MB);
  ushort_t* kh  = (ushort_t*)(ws + 40 * MB);
  ushort_t* vhT = (ushort_t*)(ws + 48 * MB);
  ushort_t* ob  = (ushort_t*)(ws + 56 * MB);
  float* meanV  = (float*)(ws + 64 * MB);

  transpose_w<<<1024, 256, 0, stream>>>(Wq, Wk, Wv, Wo, WqT, WkT, WvT, WoT);
  proj_gemm<<<768, 512, 0, stream>>>(q, k, v, WqT, WkT, WvT, pad1, pad2, qh, kh, vhT);
  meanv_kernel<<<1024, 256, 0, stream>>>(vhT, meanV);
  attn_kernel<<<dim3(64, 16), 256, 0, stream>>>(qh, kh, vhT, meanV, pad1, pad2, ob);
  out_gemm<<<256, 512, 0, stream>>>(ob, WoT, out);
}

// Round 9
// 92.966 us; speedup vs baseline: 1.1048x; 1.1048x over previous
//
#include <hip/hip_runtime.h>

#define B_ 4
#define S_ 1024
#define D_ 1024
#define H_ 16
#define BSD (B_*S_*D_)

typedef unsigned short ushort_t;
typedef __attribute__((ext_vector_type(8))) __bf16 bf16x8;
typedef __attribute__((ext_vector_type(8))) ushort_t ushortx8;
typedef __attribute__((ext_vector_type(4))) float f32x4;

__device__ __forceinline__ ushort_t f2bf(float f) {
  union { float f; unsigned int u; } x; x.f = f;
  unsigned int r = x.u + 0x7fffu + ((x.u >> 16) & 1u);
  return (ushort_t)(r >> 16);
}

__device__ __forceinline__ void gll16(const void* g, void* l) {
  __builtin_amdgcn_global_load_lds(
      (const __attribute__((address_space(1))) unsigned int*)g,
      (__attribute__((address_space(3))) unsigned int*)l, 16, 0, 0);
}

// Phase barrier with NO vmcnt: publish ds_writes, sync, fence reads after.
#define PBAR() do { asm volatile("s_waitcnt lgkmcnt(0)" ::: "memory"); \
                    __builtin_amdgcn_s_barrier(); \
                    asm volatile("" ::: "memory"); } while (0)

// ---------------- transpose weights -> bf16 [N][K] ----------------
__global__ __launch_bounds__(256) void transpose_w(
    const float* __restrict__ Wq, const float* __restrict__ Wk,
    const float* __restrict__ Wv, const float* __restrict__ Wo,
    ushort_t* __restrict__ WqT, ushort_t* __restrict__ WkT,
    ushort_t* __restrict__ WvT, ushort_t* __restrict__ WoT)
{
  __shared__ float tile[64][65];
  int blk = blockIdx.x;
  const float* src; ushort_t* dst;
  size_t sbase, dbase; int ld_src, ld_dst, r0, c0;
  if (blk < 768) {
    int tz = blk / 256;
    int rem = blk % 256; int head = rem >> 4; int kt = rem & 15;
    src = (tz == 0) ? Wq : (tz == 1) ? Wk : Wv;
    dst = (tz == 0) ? WqT : (tz == 1) ? WkT : WvT;
    sbase = (size_t)head * 1024 * 64; dbase = (size_t)head * 64 * 1024;
    ld_src = 64; ld_dst = 1024; r0 = kt * 64; c0 = 0;
  } else {
    int idx = blk - 768; src = Wo; dst = WoT;
    sbase = 0; dbase = 0; ld_src = 1024; ld_dst = 1024;
    r0 = (idx >> 4) * 64; c0 = (idx & 15) * 64;
  }
  int tid = threadIdx.x; int col = tid & 63; int rbase = tid >> 6;
  #pragma unroll
  for (int j = 0; j < 16; ++j) {
    int row = j * 4 + rbase;
    tile[row][col] = src[sbase + (size_t)(r0 + row) * ld_src + c0 + col];
  }
  __syncthreads();
  #pragma unroll
  for (int j = 0; j < 16; ++j) {
    int orow = j * 4 + rbase;   // source col
    dst[dbase + (size_t)(c0 + orow) * ld_dst + r0 + col] = f2bf(tile[col][orow]);
  }
}

// ---------------- 128x128 reg-pipelined GEMM, f32 A (proj) ----------------
// Round-5 structure (best measured). Both operands global->reg (iter t) -> LDS
// (iter t+1); PBAR has no vmcnt, loads age a full iteration before consume.
__device__ __forceinline__ void gemm_pipe_f32A(
    const float* __restrict__ Af, const ushort_t* __restrict__ BT,
    ushort_t* __restrict__ Cb, int epi, int m0, int n0, int K)
{
  __shared__ __align__(16) ushort_t As[2][128 * 64];
  __shared__ __align__(16) ushort_t Bs[2][128 * 64];
  const int tid = threadIdx.x;
  const int wave = tid >> 6, lane = tid & 63;
  const int wm = wave >> 2, wn = wave & 3;   // wave tile: 64 (m) x 32 (n)

  f32x4 acc[4][2] = {};
  float4   ra0[2][2], ra1[2][2];   // ping-pong A f32  [segment][half]
  ushortx8 rb0[2],    rb1[2];      // ping-pong B bf16 [segment]

  int offs[2], gofs[2];
  #pragma unroll
  for (int i = 0; i < 2; ++i) {
    int off = ((i * 8 + wave) << 10) + lane * 16;
    int row = off >> 7, cb = off & 127;
    int lcb = cb ^ ((row & 7) << 4);
    offs[i] = off;
    gofs[i] = row * K + (lcb >> 1);
  }

  auto loadAB = [&](float4 (&ar)[2][2], ushortx8 (&br)[2], int k0) {
    #pragma unroll
    for (int i = 0; i < 2; ++i) {
      const float* asrc = Af + (size_t)m0 * K + gofs[i] + k0;
      ar[i][0] = *(const float4*)(asrc);
      ar[i][1] = *(const float4*)(asrc + 4);
      br[i] = *(const ushortx8*)(BT + (size_t)n0 * K + gofs[i] + k0);
    }
  };
  auto writeAB = [&](int buf, const float4 (&ar)[2][2], const ushortx8 (&br)[2]) {
    #pragma unroll
    for (int i = 0; i < 2; ++i) {
      ushortx8 tv;
      #pragma unroll
      for (int j = 0; j < 4; ++j) {
        tv[j]     = f2bf(((const float*)&ar[i][0])[j]);
        tv[4 + j] = f2bf(((const float*)&ar[i][1])[j]);
      }
      *(ushortx8*)((char*)As[buf] + offs[i]) = tv;
      *(ushortx8*)((char*)Bs[buf] + offs[i]) = br[i];
    }
  };
  auto compute = [&](int buf) {
    #pragma unroll
    for (int kk = 0; kk < 2; ++kk) {
      bf16x8 af[4], bfr[2];
      #pragma unroll
      for (int mf = 0; mf < 4; ++mf) {
        int row = wm * 64 + mf * 16 + (lane & 15);
        int cb = kk * 64 + ((lane >> 4) << 4);
        af[mf] = *(const bf16x8*)((const char*)As[buf] + (row << 7) + (cb ^ ((row & 7) << 4)));
      }
      #pragma unroll
      for (int nf = 0; nf < 2; ++nf) {
        int row = wn * 32 + nf * 16 + (lane & 15);
        int cb = kk * 64 + ((lane >> 4) << 4);
        bfr[nf] = *(const bf16x8*)((const char*)Bs[buf] + (row << 7) + (cb ^ ((row & 7) << 4)));
      }
      #pragma unroll
      for (int mf = 0; mf < 4; ++mf)
        #pragma unroll
        for (int nf = 0; nf < 2; ++nf)
          acc[mf][nf] = __builtin_amdgcn_mfma_f32_16x16x32_bf16(af[mf], bfr[nf], acc[mf][nf], 0, 0, 0);
    }
  };

  const int nt = K >> 6;   // 16; even
  loadAB(ra0, rb0, 0);
  writeAB(0, ra0, rb0);          // prologue: one exposed wait for tile0
  loadAB(ra1, rb1, 64);
  PBAR();

  for (int t = 0; t < nt - 3; t += 2) {
    loadAB(ra0, rb0, (t + 2) << 6);
    __builtin_amdgcn_sched_barrier(0);
    compute(0);                  // tile t
    writeAB(1, ra1, rb1);        // tile t+1 (regs aged ~1 iteration)
    PBAR();
    loadAB(ra1, rb1, (t + 3) << 6);
    __builtin_amdgcn_sched_barrier(0);
    compute(1);                  // tile t+1
    writeAB(0, ra0, rb0);        // tile t+2
    PBAR();
  }
  // buf0 = tile nt-2; regs ra1/rb1 = tile nt-1
  compute(0);
  writeAB(1, ra1, rb1);
  PBAR();
  compute(1);

  #pragma unroll
  for (int mf = 0; mf < 4; ++mf) {
    #pragma unroll
    for (int nf = 0; nf < 2; ++nf) {
      #pragma unroll
      for (int r = 0; r < 4; ++r) {
        int m = m0 + wm * 64 + mf * 16 + ((lane >> 4) << 2) + r;
        int n = n0 + wn * 32 + nf * 16 + (lane & 15);
        float val = acc[mf][nf][r];
        if (epi == 0) {           // qh/kh: [B,H,S,64]
          int b = m >> 10, s = m & 1023, h = n >> 6, dk = n & 63;
          Cb[((((size_t)(b * H_ + h)) << 10) + s) * 64 + dk] = f2bf(val);
        } else {                  // vhT: [B,H,64,S]
          int b = m >> 10, s = m & 1023, h = n >> 6, dv = n & 63;
          Cb[((((size_t)(b * H_ + h)) * 64 + dv) << 10) + s] = f2bf(val);
        }
      }
    }
  }
}

// ---------------- 128x128 reg-pipelined GEMM, bf16 A (out_gemm) ----------------
__device__ __forceinline__ void gemm_pipe_bf16(
    const ushort_t* __restrict__ A, const ushort_t* __restrict__ BT,
    float* __restrict__ Cf, int m0, int n0, int K)
{
  __shared__ __align__(16) ushort_t As[2][128 * 64];
  __shared__ __align__(16) ushort_t Bs[2][128 * 64];
  const int tid = threadIdx.x;
  const int wave = tid >> 6, lane = tid & 63;
  const int wm = wave >> 2, wn = wave & 3;

  f32x4 acc[4][2] = {};
  ushortx8 ra0[2], ra1[2], rb0[2], rb1[2];

  int offs[2], gofs[2];
  #pragma unroll
  for (int i = 0; i < 2; ++i) {
    int off = ((i * 8 + wave) << 10) + lane * 16;
    int row = off >> 7, cb = off & 127;
    int lcb = cb ^ ((row & 7) << 4);
    offs[i] = off;
    gofs[i] = row * K + (lcb >> 1);
  }

  auto loadAB = [&](ushortx8 (&ar)[2], ushortx8 (&br)[2], int k0) {
    #pragma unroll
    for (int i = 0; i < 2; ++i) {
      ar[i] = *(const ushortx8*)(A  + (size_t)m0 * K + gofs[i] + k0);
      br[i] = *(const ushortx8*)(BT + (size_t)n0 * K + gofs[i] + k0);
    }
  };
  auto writeAB = [&](int buf, const ushortx8 (&ar)[2], const ushortx8 (&br)[2]) {
    #pragma unroll
    for (int i = 0; i < 2; ++i) {
      *(ushortx8*)((char*)As[buf] + offs[i]) = ar[i];
      *(ushortx8*)((char*)Bs[buf] + offs[i]) = br[i];
    }
  };
  auto compute = [&](int buf) {
    #pragma unroll
    for (int kk = 0; kk < 2; ++kk) {
      bf16x8 af[4], bfr[2];
      #pragma unroll
      for (int mf = 0; mf < 4; ++mf) {
        int row = wm * 64 + mf * 16 + (lane & 15);
        int cb = kk * 64 + ((lane >> 4) << 4);
        af[mf] = *(const bf16x8*)((const char*)As[buf] + (row << 7) + (cb ^ ((row & 7) << 4)));
      }
      #pragma unroll
      for (int nf = 0; nf < 2; ++nf) {
        int row = wn * 32 + nf * 16 + (lane & 15);
        int cb = kk * 64 + ((lane >> 4) << 4);
        bfr[nf] = *(const bf16x8*)((const char*)Bs[buf] + (row << 7) + (cb ^ ((row & 7) << 4)));
      }
      #pragma unroll
      for (int mf = 0; mf < 4; ++mf)
        #pragma unroll
        for (int nf = 0; nf < 2; ++nf)
          acc[mf][nf] = __builtin_amdgcn_mfma_f32_16x16x32_bf16(af[mf], bfr[nf], acc[mf][nf], 0, 0, 0);
    }
  };

  const int nt = K >> 6;
  loadAB(ra0, rb0, 0);
  writeAB(0, ra0, rb0);
  loadAB(ra1, rb1, 64);
  PBAR();

  for (int t = 0; t < nt - 3; t += 2) {
    loadAB(ra0, rb0, (t + 2) << 6);
    __builtin_amdgcn_sched_barrier(0);
    compute(0);
    writeAB(1, ra1, rb1);
    PBAR();
    loadAB(ra1, rb1, (t + 3) << 6);
    __builtin_amdgcn_sched_barrier(0);
    compute(1);
    writeAB(0, ra0, rb0);
    PBAR();
  }
  compute(0);
  writeAB(1, ra1, rb1);
  PBAR();
  compute(1);

  #pragma unroll
  for (int mf = 0; mf < 4; ++mf) {
    #pragma unroll
    for (int nf = 0; nf < 2; ++nf) {
      #pragma unroll
      for (int r = 0; r < 4; ++r) {
        int m = m0 + wm * 64 + mf * 16 + ((lane >> 4) << 2) + r;
        int n = n0 + wn * 32 + nf * 16 + (lane & 15);
        Cf[(size_t)m * 1024 + n] = acc[mf][nf][r];
      }
    }
  }
}

// proj: 1-D grid 768, bit-permuted mapping combining BOTH properties:
//   f = (c>>3)<<6 | y<<3 | (c&7)   (c = combo 0..95, y = N-tile 0..7)
// -> all 8 y-blocks of a combo share f%8 (same XCD: A-panel fetched into ONE
//    L2, fixing round-8's 4.6x FETCH explosion), and adjacent combos land on
//    different XCDs (dead q/k combos spread evenly: keeps round-8's balance).
__global__ __launch_bounds__(512, 4) void proj_gemm(
    const float* q, const float* k, const float* v,
    const ushort_t* WqT, const ushort_t* WkT, const ushort_t* WvT,
    const int* __restrict__ pad1p, const int* __restrict__ pad2p,
    ushort_t* qh, ushort_t* kh, ushort_t* vhT)
{
  int f = blockIdx.x;
  int c = ((f >> 6) << 3) | (f & 7);  // combo 0..95
  int y = (f >> 3) & 7;               // N-tile 0..7
  int z = c >> 5, x = c & 31;
  if (z < 2) {                    // q (z=0) gated by pad2, k (z=1) by pad1
    int b = x >> 3;
    int s0 = (x & 7) << 7;
    int lim = (z == 0) ? pad2p[b] : pad1p[b];
    if (s0 >= lim) return;        // wave-uniform early exit
  }
  const float* A = (z == 0) ? q : (z == 1) ? k : v;
  const ushort_t* BT = (z == 0) ? WqT : (z == 1) ? WkT : WvT;
  ushort_t* C = (z == 0) ? qh : (z == 1) ? kh : vhT;
  gemm_pipe_f32A(A, BT, C, (z == 2) ? 1 : 0, x * 128, y * 128, 1024);
}

__global__ __launch_bounds__(512, 4) void out_gemm(
    const ushort_t* o, const ushort_t* WoT, float* out)
{
  int f = blockIdx.x;
  int xcd = f & 7;
  int slot = f >> 3;              // 0..31
  int x = xcd * 4 + (slot >> 3);  // 0..31
  int y = slot & 7;
  gemm_pipe_bf16(o, WoT, out, x * 128, y * 128, 1024);
}

// ---------------- V-mean per (b,h,dv) for fully-masked rows ----------------
__global__ __launch_bounds__(256) void meanv_kernel(
    const ushort_t* __restrict__ vhT, float* __restrict__ meanV)
{
  int row = blockIdx.x * 4 + (threadIdx.x >> 6);   // bh*64 + dv
  int lane = threadIdx.x & 63;
  const ushort_t* src = vhT + ((size_t)row << 10) + lane * 16;
  float s = 0.f;
  #pragma unroll
  for (int i = 0; i < 2; ++i) {
    bf16x8 v = *(const bf16x8*)(src + i * 8);
    #pragma unroll
    for (int j = 0; j < 8; ++j) s += (float)v[j];
  }
  #pragma unroll
  for (int mm = 1; mm < 64; mm <<= 1) s += __shfl_xor(s, mm);
  if (lane == 0) meanV[row] = s * (1.0f / 1024.0f);
}

// ---------------- flash attention ----------------
__global__ __launch_bounds__(256) void attn_kernel(
    const ushort_t* __restrict__ qh, const ushort_t* __restrict__ kh,
    const ushort_t* __restrict__ vhT, const float* __restrict__ meanV,
    const int* __restrict__ pad1p, const int* __restrict__ pad2p,
    ushort_t* __restrict__ o)
{
  const int bh = blockIdx.x;
  const int b = bh >> 4, h = bh & 15;
  const int q0 = blockIdx.y << 6;
  const int pad1 = pad1p[b], pad2 = pad2p[b];
  const int tid = threadIdx.x, wave = tid >> 6, lane = tid & 63;

  if (q0 >= pad2) {   // whole tile dead: softmax of all -1e10 -> uniform -> meanV
    int dv = tid & 63;
    int rw = tid >> 6;
    ushort_t mb = f2bf(meanV[(bh << 6) + dv]);
    for (int r = rw; r < 64; r += 4)
      o[(((size_t)((b << 10) + q0 + r)) << 10) + (h << 6) + dv] = mb;
    return;
  }

  __shared__ __align__(16) ushort_t Ks[64 * 64];
  __shared__ __align__(16) ushort_t Vs[64 * 64];
  __shared__ __align__(16) ushort_t Ps[4][16 * 64];

  const ushort_t* qbase = qh + ((size_t)bh << 16);
  const ushort_t* kbase = kh + ((size_t)bh << 16);
  const ushort_t* vbase = vhT + ((size_t)bh << 16);

  const int qrow = q0 + wave * 16 + (lane & 15);
  bf16x8 qf[2];
  qf[0] = *(const bf16x8*)(qbase + (size_t)qrow * 64 + ((lane >> 4) << 3));
  qf[1] = *(const bf16x8*)(qbase + (size_t)qrow * 64 + 32 + ((lane >> 4) << 3));

  f32x4 acc[4] = {};
  float mrow[4] = { -1e30f, -1e30f, -1e30f, -1e30f };
  float lrow[4] = { 0.f, 0.f, 0.f, 0.f };
  const int ribase = q0 + wave * 16 + ((lane >> 4) << 2);

  int t_hi = min(q0 + 63, min(pad2 - 1, pad1 - 1));
  int nb = (t_hi >> 6) + 1;

  for (int kb = 0; kb < nb; ++kb) {
    const int t0 = kb << 6;
    #pragma unroll
    for (int i = 0; i < 2; ++i) {
      int off = ((i * 4 + wave) << 10) + lane * 16;
      int row = off >> 7;
      int cb = off & 127;
      int lcb = cb ^ ((row & 7) << 4);
      gll16(kbase + (size_t)(t0 + row) * 64 + (lcb >> 1), (char*)Ks + off);
      gll16(vbase + ((size_t)row << 10) + t0 + (lcb >> 1), (char*)Vs + off);
    }
    __syncthreads();

    f32x4 sc[4];
    #pragma unroll
    for (int nf = 0; nf < 4; ++nf) {
      sc[nf] = (f32x4){0.f, 0.f, 0.f, 0.f};
      #pragma unroll
      for (int kk = 0; kk < 2; ++kk) {
        int trow = nf * 16 + (lane & 15);
        int cb = kk * 64 + ((lane >> 4) << 4);
        bf16x8 kf = *(const bf16x8*)((const char*)Ks + (trow << 7) + (cb ^ ((trow & 7) << 4)));
        sc[nf] = __builtin_amdgcn_mfma_f32_16x16x32_bf16(qf[kk], kf, sc[nf], 0, 0, 0);
      }
    }

    float pv[4][4];
    #pragma unroll
    for (int r = 0; r < 4; ++r) {
      const int irow = ribase + r;
      float sval[4];
      float rmax = -1e30f;
      #pragma unroll
      for (int nf = 0; nf < 4; ++nf) {
        int t = t0 + nf * 16 + (lane & 15);
        float vv = sc[nf][r] * 0.125f;
        if (t > irow || t >= pad1) vv = -1e10f;
        sval[nf] = vv;
        rmax = fmaxf(rmax, vv);
      }
      #pragma unroll
      for (int mm = 1; mm < 16; mm <<= 1) rmax = fmaxf(rmax, __shfl_xor(rmax, mm));
      float nm = fmaxf(mrow[r], rmax);
      float fscale = __expf(mrow[r] - nm);
      float rsum = 0.f;
      #pragma unroll
      for (int nf = 0; nf < 4; ++nf) {
        float p = __expf(sval[nf] - nm);
        pv[nf][r] = p;
        rsum += p;
      }
      #pragma unroll
      for (int mm = 1; mm < 16; mm <<= 1) rsum += __shfl_xor(rsum, mm);
      mrow[r] = nm;
      lrow[r] = lrow[r] * fscale + rsum;
      #pragma unroll
      for (int dvf = 0; dvf < 4; ++dvf) acc[dvf][r] *= fscale;
    }

    #pragma unroll
    for (int nf = 0; nf < 4; ++nf) {
      #pragma unroll
      for (int r = 0; r < 4; ++r) {
        int prow = ((lane >> 4) << 2) + r;
        int cbw = (nf * 16 + (lane & 15)) * 2;
        *(ushort_t*)((char*)Ps[wave] + (prow << 7) + (cbw ^ ((prow & 7) << 4))) = f2bf(pv[nf][r]);
      }
    }

    #pragma unroll
    for (int kk = 0; kk < 2; ++kk) {
      int prow = lane & 15;
      int cb = kk * 64 + ((lane >> 4) << 4);
      bf16x8 pf = *(const bf16x8*)((const char*)Ps[wave] + (prow << 7) + (cb ^ ((prow & 7) << 4)));
      #pragma unroll
      for (int dvf = 0; dvf < 4; ++dvf) {
        int vrow = dvf * 16 + (lane & 15);
        bf16x8 vfr = *(const bf16x8*)((const char*)Vs + (vrow << 7) + (cb ^ ((vrow & 7) << 4)));
        acc[dvf] = __builtin_amdgcn_mfma_f32_16x16x32_bf16(pf, vfr, acc[dvf], 0, 0, 0);
      }
    }
    __syncthreads();
  }

  #pragma unroll
  for (int dvf = 0; dvf < 4; ++dvf) {
    #pragma unroll
    for (int r = 0; r < 4; ++r) {
      int irow = ribase + r;
      int dv = dvf * 16 + (lane & 15);
      float val;
      if (irow < pad2) val = acc[dvf][r] * (1.0f / lrow[r]);
      else val = meanV[(bh << 6) + dv];
      o[(((size_t)((b << 10) + irow)) << 10) + (h << 6) + dv] = f2bf(val);
    }
  }
}

extern "C" void kernel_launch(void* const* d_in, const int* in_sizes, int n_in,
                              void* d_out, int out_size, void* d_ws, size_t ws_size,
                              hipStream_t stream) {
  (void)in_sizes; (void)n_in; (void)out_size; (void)ws_size;
  const float* q = (const float*)d_in[0];
  const float* k = (const float*)d_in[1];
  const float* v = (const float*)d_in[2];
  const int* pad1 = (const int*)d_in[3];
  const int* pad2 = (const int*)d_in[4];
  const float* Wq = (const float*)d_in[5];
  const float* Wk = (const float*)d_in[6];
  const float* Wv = (const float*)d_in[7];
  const float* Wo = (const float*)d_in[8];
  float* out = (float*)d_out;

  char* ws = (char*)d_ws;
  const size_t MB = 1u << 20;
  ushort_t* WqT = (ushort_t*)(ws + 24 * MB);
  ushort_t* WkT = (ushort_t*)(ws + 26 * MB);
  ushort_t* WvT = (ushort_t*)(ws + 28 * MB);
  ushort_t* WoT = (ushort_t*)(ws + 30 * MB);
  ushort_t* qh  = (ushort_t*)(ws + 32 * MB);
  ushort_t* kh  = (ushort_t*)(ws + 40 * MB);
  ushort_t* vhT = (ushort_t*)(ws + 48 * MB);
  ushort_t* ob  = (ushort_t*)(ws + 56 * MB);
  float* meanV  = (float*)(ws + 64 * MB);

  transpose_w<<<1024, 256, 0, stream>>>(Wq, Wk, Wv, Wo, WqT, WkT, WvT, WoT);
  proj_gemm<<<768, 512, 0, stream>>>(q, k, v, WqT, WkT, WvT, pad1, pad2, qh, kh, vhT);
  meanv_kernel<<<1024, 256, 0, stream>>>(vhT, meanV);
  attn_kernel<<<dim3(64, 16), 256, 0, stream>>>(qh, kh, vhT, meanV, pad1, pad2, ob);
  out_gemm<<<256, 512, 0, stream>>>(ob, WoT, out);
}